// Round 1
// baseline (33859.433 us; speedup 1.0000x reference)
//
#include <hip/hip_runtime.h>
#include <hip/hip_fp16.h>

#define B_ 64
#define T_ 1024
#define IN_ 512
#define H_ 512
#define G_ 1536

typedef _Float16 h2v __attribute__((ext_vector_type(2)));
typedef _Float16 h4v __attribute__((ext_vector_type(4)));
typedef _Float16 h8v __attribute__((ext_vector_type(8)));

// ---------------------------------------------------------------------------
// Repack w_hh fp32 [b][k][g] -> fp16 k-pair-interleaved wp[b][kp][2g+e],
// kp = k/2, e = k%2. {w[2kp][g], w[2kp+1][g]} adjacent -> feeds v_dot2_f32_f16.
// Also zeroes the 64 per-batch sync counters (stream-ordered before gru_persist,
// inter-kernel visibility guaranteed by dispatch acquire/release).
// ---------------------------------------------------------------------------
__global__ __launch_bounds__(256) void convert_whh(const float* __restrict__ w,
                                                   __half* __restrict__ wp,
                                                   unsigned int* __restrict__ cnt) {
  if (blockIdx.x == 0 && threadIdx.x < 64) cnt[threadIdx.x] = 0u;
  size_t i = (size_t)blockIdx.x * 256 + threadIdx.x;  // 6,291,456 threads
  int c  = (int)(i % 384);           // g-quad index (4 g's each)
  int kp = (int)((i / 384) % 256);
  int b  = (int)(i / (384 * 256));
  const float* r0 = w + ((size_t)b * 512 + 2 * kp) * G_ + c * 4;
  const float* r1 = r0 + G_;
  float4 a = *reinterpret_cast<const float4*>(r0);
  float4 d = *reinterpret_cast<const float4*>(r1);
  __half2* dst = reinterpret_cast<__half2*>(wp + ((size_t)b * 256 + kp) * 3072 + c * 8);
  dst[0] = __floats2half2_rn(a.x, d.x);
  dst[1] = __floats2half2_rn(a.y, d.y);
  dst[2] = __floats2half2_rn(a.z, d.z);
  dst[3] = __floats2half2_rn(a.w, d.w);
}

// ---------------------------------------------------------------------------
// ih_all[b,t,g] = sum_i xs[b,t,i] * w_ih[b,i,g] + b_ih[b,g], stored fp16.
// (unchanged — fp32 VALU tiled GEMM; MFMA conversion is next round)
// ---------------------------------------------------------------------------
__global__ __launch_bounds__(256) void gemm_ih(const float* __restrict__ xs,
                                               const float* __restrict__ w_ih,
                                               const float* __restrict__ b_ih,
                                               __half* __restrict__ ih16) {
  int b  = blockIdx.z;
  int n0 = blockIdx.x * 64;
  int m0 = blockIdx.y * 64;
  const float* A  = xs   + (size_t)b * T_ * IN_;
  const float* Bw = w_ih + (size_t)b * IN_ * G_;

  __shared__ float As[16][68];
  __shared__ float Bs[16][64];

  int tid = threadIdx.x;
  int tx = tid & 15, ty = tid >> 4;
  int lam = tid >> 2;
  int lak = (tid & 3) * 4;
  int lbk = tid >> 4;
  int lbn = (tid & 15) * 4;

  float acc[4][4] = {};

  for (int k0 = 0; k0 < IN_; k0 += 16) {
    float4 av = *reinterpret_cast<const float4*>(A  + (size_t)(m0 + lam) * IN_ + k0 + lak);
    float4 bv = *reinterpret_cast<const float4*>(Bw + (size_t)(k0 + lbk) * G_ + n0 + lbn);
    As[lak + 0][lam] = av.x;
    As[lak + 1][lam] = av.y;
    As[lak + 2][lam] = av.z;
    As[lak + 3][lam] = av.w;
    *reinterpret_cast<float4*>(&Bs[lbk][lbn]) = bv;
    __syncthreads();
#pragma unroll
    for (int kk = 0; kk < 16; ++kk) {
      float4 aq = *reinterpret_cast<const float4*>(&As[kk][ty * 4]);
      float4 bq = *reinterpret_cast<const float4*>(&Bs[kk][tx * 4]);
      float a[4] = {aq.x, aq.y, aq.z, aq.w};
      float bb[4] = {bq.x, bq.y, bq.z, bq.w};
#pragma unroll
      for (int i = 0; i < 4; ++i)
#pragma unroll
        for (int j = 0; j < 4; ++j) acc[i][j] += a[i] * bb[j];
    }
    __syncthreads();
  }

  float4 bias = *reinterpret_cast<const float4*>(b_ih + (size_t)b * G_ + n0 + tx * 4);
#pragma unroll
  for (int i = 0; i < 4; ++i) {
    size_t row = (size_t)b * T_ + m0 + ty * 4 + i;
    __half2* dst = reinterpret_cast<__half2*>(ih16 + row * G_ + n0 + tx * 4);
    dst[0] = __floats2half2_rn(acc[i][0] + bias.x, acc[i][1] + bias.y);
    dst[1] = __floats2half2_rn(acc[i][2] + bias.z, acc[i][3] + bias.w);
  }
}

// ---------------------------------------------------------------------------
// Persistent recurrence kernel. Grid (8 grp, 64 batch) = 512 blocks x 256 thr.
// Each thread pins its w_hh slice (6 g's x 64 k = 96 h4v = 192 VGPRs) in
// registers ONCE, then iterates all T=1024 steps internally.
//
// Co-residency: __launch_bounds__(256,2) caps VGPR at 256 -> 2 blocks/CU ->
// 512 blocks = exact chip capacity. Insurance: linear block id = grp + 8*b
// (x fastest), so any schedule prefix contains whole batches -> no deadlock
// even at reduced residency (sync is intra-batch only).
//
// Sync: cnt[b] monotonic counter. Producer: __syncthreads -> release
// fetch_add(1, agent). Consumer step t: spin until cnt[b] >= 8*t (relaxed +
// s_sleep), one acquire load, __syncthreads. cnt >= 8(t+1) iff ALL 8 blocks
// finished step t (no block can be >1 step ahead of the gate).
// ---------------------------------------------------------------------------
__global__ __launch_bounds__(256, 2) void gru_persist(
    const __half* __restrict__ wp,    // [b][256][3072] packed
    const float* __restrict__ b_hh,   // [b][g]
    const __half* __restrict__ ih16,  // [b][t][g]
    const float* __restrict__ state,  // [b][h]
    float* __restrict__ out,          // [b][t][h]
    float* __restrict__ fin,          // [b][h]
    unsigned int* __restrict__ cnt) { // [64]
  __shared__ h2v hsh2[256];                       // h as fp16 k-pairs
  __shared__ __align__(16) float hsh[512];        // h fp32 for hy formula
  __shared__ __align__(16) float part[8][192];
  __shared__ float gsh[192];

  int grp = blockIdx.x;    // 0..7  -> j0 = grp*64
  int b   = blockIdx.y;    // 0..63
  int tid = threadIdx.x;   // 0..255
  int kq  = tid >> 5;      // 0..7  k-split (64 k's = 32 kp's each)
  int c   = tid & 31;      // 0..31 g-chunk (6 g's each)
  int j0  = grp * 64;

  // ---- pin weight slice in registers (once) ----
  // local g index gl in [0,192): global g = (gl>>6)*512 + j0 + (gl&63).
  // h4v at fp16 offset 2g = {w(2kp,g), w(2kp+1,g), w(2kp,g+1), w(2kp+1,g+1)}.
  h4v W[32][3];
  {
    const char* base = (const char*)wp + ((size_t)b * 256 + (size_t)kq * 32) * 6144;
#pragma unroll
    for (int p = 0; p < 3; ++p) {
      int gl = (c * 3 + p) * 2;                      // even
      int g  = (gl >> 6) * 512 + j0 + (gl & 63);
      const char* colp = base + (size_t)4 * g;
#pragma unroll
      for (int i = 0; i < 32; ++i)
        W[i][p] = *reinterpret_cast<const h4v*>(colp + (size_t)i * 6144);
    }
  }

  float bh = 0.f;
  if (tid < 192) bh = b_hh[(size_t)b * G_ + (tid >> 6) * 512 + j0 + (tid & 63)];

  const int kbase = kq * 32;

#pragma unroll 1
  for (int t = 0; t < T_; ++t) {
    // prefetch this step's ih slice (independent of h; issued before the spin,
    // barriers below keep it from sinking past the dot phase)
    float i_r = 0.f, i_i = 0.f, i_n = 0.f;
    if (tid < 64) {
      const __half* q = ih16 + ((size_t)b * T_ + t) * G_ + j0 + tid;
      i_r = __half2float(q[0]);
      i_i = __half2float(q[512]);
      i_n = __half2float(q[1024]);
    }

    if (t > 0) {
      if (tid == 0) {
        unsigned target = 8u * (unsigned)t;
        while (__hip_atomic_load(&cnt[b], __ATOMIC_RELAXED, __HIP_MEMORY_SCOPE_AGENT) < target)
          __builtin_amdgcn_s_sleep(2);
        (void)__hip_atomic_load(&cnt[b], __ATOMIC_ACQUIRE, __HIP_MEMORY_SCOPE_AGENT);
      }
      __syncthreads();
    }

    const float* hp = (t == 0) ? (state + (size_t)b * H_)
                               : (out + ((size_t)b * T_ + (t - 1)) * H_);
    float2 hv = *reinterpret_cast<const float2*>(hp + tid * 2);
    h2v h2; h2[0] = (_Float16)hv.x; h2[1] = (_Float16)hv.y;
    hsh2[tid] = h2;
    *reinterpret_cast<float2*>(&hsh[2 * tid]) = hv;
    __syncthreads();

    float a0 = 0.f, a1 = 0.f, a2 = 0.f, a3 = 0.f, a4 = 0.f, a5 = 0.f;
#pragma unroll
    for (int i = 0; i < 32; ++i) {
      h2v hk = hsh2[kbase + i];
      a0 = __builtin_amdgcn_fdot2(__builtin_shufflevector(W[i][0], W[i][0], 0, 1), hk, a0, false);
      a1 = __builtin_amdgcn_fdot2(__builtin_shufflevector(W[i][0], W[i][0], 2, 3), hk, a1, false);
      a2 = __builtin_amdgcn_fdot2(__builtin_shufflevector(W[i][1], W[i][1], 0, 1), hk, a2, false);
      a3 = __builtin_amdgcn_fdot2(__builtin_shufflevector(W[i][1], W[i][1], 2, 3), hk, a3, false);
      a4 = __builtin_amdgcn_fdot2(__builtin_shufflevector(W[i][2], W[i][2], 0, 1), hk, a4, false);
      a5 = __builtin_amdgcn_fdot2(__builtin_shufflevector(W[i][2], W[i][2], 2, 3), hk, a5, false);
    }
    {
      float2* pp = reinterpret_cast<float2*>(&part[kq][c * 6]);
      pp[0] = {a0, a1};
      pp[1] = {a2, a3};
      pp[2] = {a4, a5};
    }
    __syncthreads();

    if (tid < 192) {
      float s = 0.f;
#pragma unroll
      for (int q = 0; q < 8; ++q) s += part[q][tid];
      gsh[tid] = s + bh;
    }
    __syncthreads();

    if (tid < 64) {
      int j = j0 + tid;
      float h_r = gsh[tid], h_i = gsh[64 + tid], h_n = gsh[128 + tid];
      float rg = 1.f / (1.f + __expf(-(i_r + h_r)));
      float ig = 1.f / (1.f + __expf(-(i_i + h_i)));
      float ng = tanhf(i_n + rg * h_n);
      float h  = hsh[j];
      float hy = ng + ig * (h - ng);
      out[((size_t)b * T_ + t) * H_ + j] = hy;
      if (t == T_ - 1) fin[(size_t)b * H_ + j] = hy;
    }
    __syncthreads();  // hy stores done block-wide; also protects LDS reuse

    if (tid == 0)
      (void)__hip_atomic_fetch_add(&cnt[b], 1u, __ATOMIC_RELEASE, __HIP_MEMORY_SCOPE_AGENT);
  }
}

extern "C" void kernel_launch(void* const* d_in, const int* in_sizes, int n_in,
                              void* d_out, int out_size, void* d_ws, size_t ws_size,
                              hipStream_t stream) {
  (void)in_sizes; (void)n_in; (void)out_size; (void)ws_size;
  const float* xs    = (const float*)d_in[0];
  const float* state = (const float*)d_in[1];
  const float* w_ih  = (const float*)d_in[2];
  const float* w_hh  = (const float*)d_in[3];
  const float* b_ih  = (const float*)d_in[4];
  const float* b_hh  = (const float*)d_in[5];
  float* out = (float*)d_out;
  float* fin = out + (size_t)B_ * T_ * H_;

  unsigned int* cnt = (unsigned int*)d_ws;            // 64 counters (zeroed by convert_whh)
  __half* wp   = (__half*)((char*)d_ws + 1024);       // 96 MiB packed fp16 w_hh
  __half* ih16 = wp + (size_t)B_ * H_ * G_;           // 192 MiB fp16 ih_all

  convert_whh<<<(B_ * 256 * 384) / 256, 256, 0, stream>>>(w_hh, wp, cnt);

  dim3 ggrid(G_ / 64, T_ / 64, B_);
  gemm_ih<<<ggrid, 256, 0, stream>>>(xs, w_ih, b_ih, ih16);

  gru_persist<<<dim3(8, B_), 256, 0, stream>>>(wp, b_hh, ih16, state, out, fin, cnt);
}

// Round 2
// 14564.517 us; speedup vs baseline: 2.3248x; 2.3248x over previous
//
#include <hip/hip_runtime.h>
#include <hip/hip_fp16.h>

#define B_ 64
#define T_ 1024
#define IN_ 512
#define H_ 512
#define G_ 1536

typedef _Float16 h2v __attribute__((ext_vector_type(2)));
typedef _Float16 h4v __attribute__((ext_vector_type(4)));
typedef _Float16 h8v __attribute__((ext_vector_type(8)));

// ---------------------------------------------------------------------------
// Repack w_hh fp32 [b][k][g] -> fp16 k-pair-interleaved wp[b][kp][2g+e],
// kp = k/2, e = k%2. {w[2kp][g], w[2kp+1][g]} adjacent -> feeds v_dot2_f32_f16.
// Also zeroes the 64 per-batch sync counters (padded to 128 B apart).
// ---------------------------------------------------------------------------
__global__ __launch_bounds__(256) void convert_whh(const float* __restrict__ w,
                                                   __half* __restrict__ wp,
                                                   unsigned int* __restrict__ cnt) {
  if (blockIdx.x == 0 && threadIdx.x < 64) cnt[threadIdx.x * 32] = 0u;
  size_t i = (size_t)blockIdx.x * 256 + threadIdx.x;  // 6,291,456 threads
  int c  = (int)(i % 384);           // g-quad index (4 g's each)
  int kp = (int)((i / 384) % 256);
  int b  = (int)(i / (384 * 256));
  const float* r0 = w + ((size_t)b * 512 + 2 * kp) * G_ + c * 4;
  const float* r1 = r0 + G_;
  float4 a = *reinterpret_cast<const float4*>(r0);
  float4 d = *reinterpret_cast<const float4*>(r1);
  __half2* dst = reinterpret_cast<__half2*>(wp + ((size_t)b * 256 + kp) * 3072 + c * 8);
  dst[0] = __floats2half2_rn(a.x, d.x);
  dst[1] = __floats2half2_rn(a.y, d.y);
  dst[2] = __floats2half2_rn(a.z, d.z);
  dst[3] = __floats2half2_rn(a.w, d.w);
}

// ---------------------------------------------------------------------------
// ih_all[b,t,g] = sum_i xs[b,t,i] * w_ih[b,i,g] + b_ih[b,g], stored fp16.
// (unchanged — fp32 VALU tiled GEMM; MFMA conversion once recurrence is fixed)
// ---------------------------------------------------------------------------
__global__ __launch_bounds__(256) void gemm_ih(const float* __restrict__ xs,
                                               const float* __restrict__ w_ih,
                                               const float* __restrict__ b_ih,
                                               __half* __restrict__ ih16) {
  int b  = blockIdx.z;
  int n0 = blockIdx.x * 64;
  int m0 = blockIdx.y * 64;
  const float* A  = xs   + (size_t)b * T_ * IN_;
  const float* Bw = w_ih + (size_t)b * IN_ * G_;

  __shared__ float As[16][68];
  __shared__ float Bs[16][64];

  int tid = threadIdx.x;
  int tx = tid & 15, ty = tid >> 4;
  int lam = tid >> 2;
  int lak = (tid & 3) * 4;
  int lbk = tid >> 4;
  int lbn = (tid & 15) * 4;

  float acc[4][4] = {};

  for (int k0 = 0; k0 < IN_; k0 += 16) {
    float4 av = *reinterpret_cast<const float4*>(A  + (size_t)(m0 + lam) * IN_ + k0 + lak);
    float4 bv = *reinterpret_cast<const float4*>(Bw + (size_t)(k0 + lbk) * G_ + n0 + lbn);
    As[lak + 0][lam] = av.x;
    As[lak + 1][lam] = av.y;
    As[lak + 2][lam] = av.z;
    As[lak + 3][lam] = av.w;
    *reinterpret_cast<float4*>(&Bs[lbk][lbn]) = bv;
    __syncthreads();
#pragma unroll
    for (int kk = 0; kk < 16; ++kk) {
      float4 aq = *reinterpret_cast<const float4*>(&As[kk][ty * 4]);
      float4 bq = *reinterpret_cast<const float4*>(&Bs[kk][tx * 4]);
      float a[4] = {aq.x, aq.y, aq.z, aq.w};
      float bb[4] = {bq.x, bq.y, bq.z, bq.w};
#pragma unroll
      for (int i = 0; i < 4; ++i)
#pragma unroll
        for (int j = 0; j < 4; ++j) acc[i][j] += a[i] * bb[j];
    }
    __syncthreads();
  }

  float4 bias = *reinterpret_cast<const float4*>(b_ih + (size_t)b * G_ + n0 + tx * 4);
#pragma unroll
  for (int i = 0; i < 4; ++i) {
    size_t row = (size_t)b * T_ + m0 + ty * 4 + i;
    __half2* dst = reinterpret_cast<__half2*>(ih16 + row * G_ + n0 + tx * 4);
    dst[0] = __floats2half2_rn(acc[i][0] + bias.x, acc[i][1] + bias.y);
    dst[1] = __floats2half2_rn(acc[i][2] + bias.z, acc[i][3] + bias.w);
  }
}

// ---------------------------------------------------------------------------
// Persistent recurrence kernel. Grid (8 grp, 64 batch) = 512 blocks x 256 thr.
// Each thread pins its w_hh slice (6 g's x 64 k = 96 h4v = 192 VGPRs) in
// registers ONCE (asm-pinned so the compiler CANNOT rematerialize the loads
// inside the t-loop — R1 failure mode: VGPR=120, weights re-read from L3
// every step), then iterates all T=1024 steps internally.
//
// Co-residency: __launch_bounds__(256,2) = min 2 waves/EU -> VGPR cap 256 ->
// 2 blocks/CU -> 512 blocks = exact chip capacity. Insurance: linear id =
// grp + 8*b (x fastest), so any schedule prefix contains whole batches ->
// no deadlock even at reduced residency (sync is intra-batch only).
//
// Sync: cnt[b*32] monotonic counter (128 B apart -> no false sharing).
// Producer: __syncthreads -> release fetch_add(1, agent). Consumer step t:
// spin until cnt >= 8*t (relaxed + s_sleep), one acquire load, __syncthreads.
// ---------------------------------------------------------------------------
__global__ __launch_bounds__(256, 2) void gru_persist(
    const __half* __restrict__ wp,    // [b][256][3072] packed
    const float* __restrict__ b_hh,   // [b][g]
    const __half* __restrict__ ih16,  // [b][t][g]
    const float* __restrict__ state,  // [b][h]
    float* __restrict__ out,          // [b][t][h]
    float* __restrict__ fin,          // [b][h]
    unsigned int* __restrict__ cnt) { // [64*32] padded
  __shared__ h2v hsh2[256];                       // h as fp16 k-pairs
  __shared__ __align__(16) float hsh[512];        // h fp32 for hy formula
  __shared__ __align__(16) float part[8][192];
  __shared__ float gsh[192];

  int grp = blockIdx.x;    // 0..7  -> j0 = grp*64
  int b   = blockIdx.y;    // 0..63
  int tid = threadIdx.x;   // 0..255
  int kq  = tid >> 5;      // 0..7  k-split (64 k's = 32 kp's each)
  int c   = tid & 31;      // 0..31 g-chunk (6 g's each)
  int j0  = grp * 64;

  // ---- pin weight slice in registers (once) ----
  // local g index gl in [0,192): global g = (gl>>6)*512 + j0 + (gl&63).
  // h4v at fp16 offset 2g = {w(2kp,g), w(2kp+1,g), w(2kp,g+1), w(2kp+1,g+1)}.
  h4v W[32][3];
  {
    const char* base = (const char*)wp + ((size_t)b * 256 + (size_t)kq * 32) * 6144;
#pragma unroll
    for (int p = 0; p < 3; ++p) {
      int gl = (c * 3 + p) * 2;                      // even
      int g  = (gl >> 6) * 512 + j0 + (gl & 63);
      const char* colp = base + (size_t)4 * g;
#pragma unroll
      for (int i = 0; i < 32; ++i)
        W[i][p] = *reinterpret_cast<const h4v*>(colp + (size_t)i * 6144);
    }
  }
  // Make W opaque: values become asm outputs -> cannot be rematerialized by
  // re-loading inside the t-loop; forces 192 live VGPRs for the duration.
#pragma unroll
  for (int i = 0; i < 32; ++i)
    asm volatile("" : "+v"(W[i][0]), "+v"(W[i][1]), "+v"(W[i][2]));

  float bh = 0.f;
  if (tid < 192) bh = b_hh[(size_t)b * G_ + (tid >> 6) * 512 + j0 + (tid & 63)];

  const int kbase = kq * 32;
  unsigned int* flag = cnt + (size_t)b * 32;

#pragma unroll 1
  for (int t = 0; t < T_; ++t) {
    // prefetch this step's ih slice (independent of h; issued before the spin)
    float i_r = 0.f, i_i = 0.f, i_n = 0.f;
    if (tid < 64) {
      const __half* q = ih16 + ((size_t)b * T_ + t) * G_ + j0 + tid;
      i_r = __half2float(q[0]);
      i_i = __half2float(q[512]);
      i_n = __half2float(q[1024]);
    }

    if (t > 0) {
      if (tid == 0) {
        unsigned target = 8u * (unsigned)t;
        while (__hip_atomic_load(flag, __ATOMIC_RELAXED, __HIP_MEMORY_SCOPE_AGENT) < target)
          __builtin_amdgcn_s_sleep(2);
        (void)__hip_atomic_load(flag, __ATOMIC_ACQUIRE, __HIP_MEMORY_SCOPE_AGENT);
      }
      __syncthreads();
    }

    const float* hp = (t == 0) ? (state + (size_t)b * H_)
                               : (out + ((size_t)b * T_ + (t - 1)) * H_);
    float2 hv = *reinterpret_cast<const float2*>(hp + tid * 2);
    h2v h2; h2[0] = (_Float16)hv.x; h2[1] = (_Float16)hv.y;
    hsh2[tid] = h2;
    *reinterpret_cast<float2*>(&hsh[2 * tid]) = hv;
    __syncthreads();

    float a0 = 0.f, a1 = 0.f, a2 = 0.f, a3 = 0.f, a4 = 0.f, a5 = 0.f;
#pragma unroll
    for (int i = 0; i < 32; ++i) {
      h2v hk = hsh2[kbase + i];
      a0 = __builtin_amdgcn_fdot2(__builtin_shufflevector(W[i][0], W[i][0], 0, 1), hk, a0, false);
      a1 = __builtin_amdgcn_fdot2(__builtin_shufflevector(W[i][0], W[i][0], 2, 3), hk, a1, false);
      a2 = __builtin_amdgcn_fdot2(__builtin_shufflevector(W[i][1], W[i][1], 0, 1), hk, a2, false);
      a3 = __builtin_amdgcn_fdot2(__builtin_shufflevector(W[i][1], W[i][1], 2, 3), hk, a3, false);
      a4 = __builtin_amdgcn_fdot2(__builtin_shufflevector(W[i][2], W[i][2], 0, 1), hk, a4, false);
      a5 = __builtin_amdgcn_fdot2(__builtin_shufflevector(W[i][2], W[i][2], 2, 3), hk, a5, false);
    }
    {
      float2* pp = reinterpret_cast<float2*>(&part[kq][c * 6]);
      pp[0] = {a0, a1};
      pp[1] = {a2, a3};
      pp[2] = {a4, a5};
    }
    __syncthreads();

    if (tid < 192) {
      float s = 0.f;
#pragma unroll
      for (int q = 0; q < 8; ++q) s += part[q][tid];
      gsh[tid] = s + bh;
    }
    __syncthreads();

    if (tid < 64) {
      int j = j0 + tid;
      float h_r = gsh[tid], h_i = gsh[64 + tid], h_n = gsh[128 + tid];
      float rg = 1.f / (1.f + __expf(-(i_r + h_r)));
      float ig = 1.f / (1.f + __expf(-(i_i + h_i)));
      float ng = tanhf(i_n + rg * h_n);
      float h  = hsh[j];
      float hy = ng + ig * (h - ng);
      out[((size_t)b * T_ + t) * H_ + j] = hy;
      if (t == T_ - 1) fin[(size_t)b * H_ + j] = hy;
    }
    __syncthreads();  // hy stores issued block-wide; also protects LDS reuse

    if (tid == 0)
      (void)__hip_atomic_fetch_add(flag, 1u, __ATOMIC_RELEASE, __HIP_MEMORY_SCOPE_AGENT);
  }
}

extern "C" void kernel_launch(void* const* d_in, const int* in_sizes, int n_in,
                              void* d_out, int out_size, void* d_ws, size_t ws_size,
                              hipStream_t stream) {
  (void)in_sizes; (void)n_in; (void)out_size; (void)ws_size;
  const float* xs    = (const float*)d_in[0];
  const float* state = (const float*)d_in[1];
  const float* w_ih  = (const float*)d_in[2];
  const float* w_hh  = (const float*)d_in[3];
  const float* b_ih  = (const float*)d_in[4];
  const float* b_hh  = (const float*)d_in[5];
  float* out = (float*)d_out;
  float* fin = out + (size_t)B_ * T_ * H_;

  unsigned int* cnt = (unsigned int*)d_ws;            // 64 counters, 128 B apart
  __half* wp   = (__half*)((char*)d_ws + 8192);       // 96 MiB packed fp16 w_hh
  __half* ih16 = wp + (size_t)B_ * H_ * G_;           // 192 MiB fp16 ih_all

  convert_whh<<<(B_ * 256 * 384) / 256, 256, 0, stream>>>(w_hh, wp, cnt);

  dim3 ggrid(G_ / 64, T_ / 64, B_);
  gemm_ih<<<ggrid, 256, 0, stream>>>(xs, w_ih, b_ih, ih16);

  gru_persist<<<dim3(8, B_), 256, 0, stream>>>(wp, b_hh, ih16, state, out, fin, cnt);
}